// Round 3
// baseline (288.819 us; speedup 1.0000x reference)
//
#include <hip/hip_runtime.h>
#include <stdint.h>

// GeoAwarePooling B=4, N=40000, C=128, V=4.
// xyz is broadcast across views -> per-point MLP runs once over B*N points.
// v3: XOR-swizzled LDS weight tiles (2-way conflicts), z2 bf16 round-trip
// instead of recompute, 2-tile ILP per wave, static LDS.

#define NPTS 40000
#define CD   128

typedef __attribute__((ext_vector_type(8))) short bf8_t;
typedef __attribute__((ext_vector_type(4))) float f4_t;

__device__ __forceinline__ unsigned short f2bfu(float f){
  unsigned u = __float_as_uint(f);
  u += 0x7FFFu + ((u>>16)&1u);               // RNE
  return (unsigned short)(u>>16);
}
__device__ __forceinline__ float bfhi_f(float f){   // f rounded to bf16, as f32
  return __uint_as_float(((unsigned)f2bfu(f))<<16);
}
__device__ __forceinline__ unsigned pk2(float a, float b){
  return (unsigned)f2bfu(a) | ((unsigned)f2bfu(b)<<16);
}
__device__ __forceinline__ float uplo(unsigned u){ return __uint_as_float(u<<16); }
__device__ __forceinline__ float uphi(unsigned u){ return __uint_as_float(u & 0xFFFF0000u); }
__device__ __forceinline__ unsigned fenc(float f){  // order-preserving key
  unsigned u = __float_as_uint(f);
  return (u & 0x80000000u) ? ~u : (u | 0x80000000u);
}
__device__ __forceinline__ float fdec(unsigned k){
  return (k & 0x80000000u) ? __uint_as_float(k & 0x7FFFFFFFu) : __uint_as_float(~k);
}
__device__ __forceinline__ bf8_t mkbf8(unsigned a,unsigned b,unsigned c,unsigned d){
  union{ bf8_t v; unsigned u[4]; } r;
  r.u[0]=a; r.u[1]=b; r.u[2]=c; r.u[3]=d;
  return r.v;
}
// swizzled element index for a [128][128] bf16 LDS tile, row stride 256B.
// 16B slot s stored at s ^ (row&7): quarter-wave b128 reads land on 8 distinct
// 16B slots (2 lanes each) -> ~2-way, vs 16-way unswizzled.
__device__ __forceinline__ int swzA(int row, int k){
  return row*128 + ((((k>>3) ^ (row&7)))<<3) + (k&7);
}

__global__ __launch_bounds__(256)
void k_init(unsigned* __restrict__ kmax, unsigned* __restrict__ kmin,
            float* __restrict__ denom, float* __restrict__ pool_acc){
  int t = blockIdx.x*256 + threadIdx.x;
  if (t < 512){ kmax[t] = 0u; kmin[t] = 0xFFFFFFFFu; }
  if (t < 16) denom[t] = 0.f;
  if (t < 2048) pool_acc[t] = 0.f;
}

// ---------------------------------------------------------------------------
// Phase A: y=xyz@W1+b1; h=relu(LN1(y)); z2 = (a2-mu)/sigma  (pre-affine LN2)
// stored bf16 to global. 2 tiles (32 pts) per wave iteration, 2 iterations.
// GEMM form D[128c][16pt]; lane holds one point's 32 channels.
// ---------------------------------------------------------------------------
__global__ __launch_bounds__(256, 2)
void k_mlpA(const float* __restrict__ xyz,
            const float* __restrict__ W1, const float* __restrict__ b1,
            const float* __restrict__ g1, const float* __restrict__ be1,
            const float* __restrict__ W2, const float* __restrict__ b2,
            unsigned short* __restrict__ z2)
{
  __shared__ unsigned short W2T[CD*CD];      // 32 KiB swizzled
  __shared__ unsigned short Hb[8*16*CD];     // 4 waves x 2 tiles x [16][128] swizzled

  const int tid = threadIdx.x;
  for (int q = tid; q < 8192; q += 256){
    int c = q & 127, k = (q >> 7) * 2;
    float f0 = W2[k*CD + c], f1 = W2[(k+1)*CD + c];
    *reinterpret_cast<unsigned*>(&W2T[swzA(c, k)]) = pk2(f0, f1);
  }
  __syncthreads();

  const int wave = tid>>6, lane = tid&63;
  const int m = lane&15, g = lane>>4;
  const int W = blockIdx.x*4 + wave;         // 0..2499
  const int b = W/625, wrem = W%625;
  const float* xyzb = xyz + (size_t)(3*b)*NPTS;
  const size_t bo = (size_t)b*NPTS;

  // layer-1 A-fragments (W1,b1 hi/lo split for fp32-exact K=3 matmul)
  bf8_t A1[8];
#pragma unroll
  for (int mt=0; mt<8; ++mt){
    int c = 16*mt + m;
    float w0=W1[c], w1=W1[CD+c], w2=W1[2*CD+c], bb=b1[c];
    unsigned u0=0,u1=0,u2=0,u3=0;
    if (g==0){
      u0 = pk2(w0,w1);
      u1 = pk2(w2,w0);
      u2 = pk2(w1,w2);
      u3 = pk2(w0-bfhi_f(w0), w1-bfhi_f(w1));
    } else if (g==1){
      u0 = pk2(w2-bfhi_f(w2), bb);
      u1 = pk2(bb-bfhi_f(bb), 0.f);
    }
    A1[mt] = mkbf8(u0,u1,u2,u3);
  }

  unsigned g1p[16], be1p[16], b2p[16];
#pragma unroll
  for (int j=0;j<16;++j){
    int i0=2*j, i1=2*j+1;
    int c0 = 16*(i0>>2) + 4*g + (i0&3);
    int c1 = 16*(i1>>2) + 4*g + (i1&3);
    g1p[j]  = pk2(g1[c0],  g1[c1]);
    be1p[j] = pk2(be1[c0], be1[c1]);
    b2p[j]  = pk2(b2[c0],  b2[c1]);
  }

  unsigned short* HA  = &Hb[(wave*2+0)*16*CD];
  unsigned short* HBt = &Hb[(wave*2+1)*16*CD];

  for (int u = 0; u < 2; ++u){
    const int pb = wrem + 625*u;
    const int nA = 32*pb + m, nB = nA + 16;

    float pxA = xyzb[0*NPTS+nA], pyA = xyzb[1*NPTS+nA], pzA = xyzb[2*NPTS+nA];
    float pxB = xyzb[0*NPTS+nB], pyB = xyzb[1*NPTS+nB], pzB = xyzb[2*NPTS+nB];

    bf8_t B1A, B1B;
    {
      unsigned a0=0,a1=0,a2=0,a3=0, c0=0,c1=0,c2=0,c3=0;
      if (g==0){
        a0 = pk2(pxA,pyA);
        a1 = pk2(pzA, pxA-bfhi_f(pxA));
        a2 = pk2(pyA-bfhi_f(pyA), pzA-bfhi_f(pzA));
        a3 = pk2(pxA,pyA);
        c0 = pk2(pxB,pyB);
        c1 = pk2(pzB, pxB-bfhi_f(pxB));
        c2 = pk2(pyB-bfhi_f(pyB), pzB-bfhi_f(pzB));
        c3 = pk2(pxB,pyB);
      } else if (g==1){
        a0 = pk2(pzA, 1.0f); a1 = pk2(1.0f, 0.f);
        c0 = pk2(pzB, 1.0f); c1 = pk2(1.0f, 0.f);
      }
      B1A = mkbf8(a0,a1,a2,a3);
      B1B = mkbf8(c0,c1,c2,c3);
    }

    f4_t yA[8], yB[8];
#pragma unroll
    for (int mt=0;mt<8;++mt){
      yA[mt] = __builtin_amdgcn_mfma_f32_16x16x32_bf16(A1[mt], B1A, (f4_t){0.f,0.f,0.f,0.f}, 0,0,0);
      yB[mt] = __builtin_amdgcn_mfma_f32_16x16x32_bf16(A1[mt], B1B, (f4_t){0.f,0.f,0.f,0.f}, 0,0,0);
    }

    // LN1 (both tiles)
    float s1A=0.f,s2A=0.f,s1B=0.f,s2B=0.f;
#pragma unroll
    for (int mt=0;mt<8;++mt)
#pragma unroll
      for (int r2=0;r2<4;++r2){
        float vA=yA[mt][r2]; s1A+=vA; s2A+=vA*vA;
        float vB=yB[mt][r2]; s1B+=vB; s2B+=vB*vB;
      }
    s1A += __shfl_xor(s1A,16); s1A += __shfl_xor(s1A,32);
    s2A += __shfl_xor(s2A,16); s2A += __shfl_xor(s2A,32);
    s1B += __shfl_xor(s1B,16); s1B += __shfl_xor(s1B,32);
    s2B += __shfl_xor(s2B,16); s2B += __shfl_xor(s2B,32);
    float muA = s1A*(1.f/128.f);
    float rsA = rsqrtf(fmaxf(s2A*(1.f/128.f)-muA*muA,0.f)+1e-5f);
    float muB = s1B*(1.f/128.f);
    float rsB = rsqrtf(fmaxf(s2B*(1.f/128.f)-muB*muB,0.f)+1e-5f);

#pragma unroll
    for (int mt=0;mt<8;++mt){
      unsigned gA=g1p[2*mt], gB2=g1p[2*mt+1], bA=be1p[2*mt], bB2=be1p[2*mt+1];
      int ho = m*128 + (((2*mt+(g>>1)) ^ (m&7))<<3) + 4*(g&1);
      {
        float h0 = fmaxf(0.f, fmaf((yA[mt][0]-muA)*rsA, uplo(gA), uplo(bA)));
        float h1 = fmaxf(0.f, fmaf((yA[mt][1]-muA)*rsA, uphi(gA), uphi(bA)));
        float h2 = fmaxf(0.f, fmaf((yA[mt][2]-muA)*rsA, uplo(gB2), uplo(bB2)));
        float h3 = fmaxf(0.f, fmaf((yA[mt][3]-muA)*rsA, uphi(gB2), uphi(bB2)));
        uint2 wv; wv.x = pk2(h0,h1); wv.y = pk2(h2,h3);
        *reinterpret_cast<uint2*>(&HA[ho]) = wv;
      }
      {
        float h0 = fmaxf(0.f, fmaf((yB[mt][0]-muB)*rsB, uplo(gA), uplo(bA)));
        float h1 = fmaxf(0.f, fmaf((yB[mt][1]-muB)*rsB, uphi(gA), uphi(bA)));
        float h2 = fmaxf(0.f, fmaf((yB[mt][2]-muB)*rsB, uplo(gB2), uplo(bB2)));
        float h3 = fmaxf(0.f, fmaf((yB[mt][3]-muB)*rsB, uphi(gB2), uphi(bB2)));
        uint2 wv; wv.x = pk2(h0,h1); wv.y = pk2(h2,h3);
        *reinterpret_cast<uint2*>(&HBt[ho]) = wv;
      }
    }

    // GEMM2 (shared A-fragments, 2 B-chains)
    f4_t aA[8], aB[8];
#pragma unroll
    for (int mt=0;mt<8;++mt){ aA[mt]=(f4_t){0.f,0.f,0.f,0.f}; aB[mt]=(f4_t){0.f,0.f,0.f,0.f}; }
#pragma unroll
    for (int ks=0;ks<4;++ks){
      const int ro = (((4*ks+g) ^ (m&7))<<3);
      bf8_t BfA = *reinterpret_cast<const bf8_t*>(&HA[m*128 + ro]);
      bf8_t BfB = *reinterpret_cast<const bf8_t*>(&HBt[m*128 + ro]);
#pragma unroll
      for (int mt=0;mt<8;++mt){
        bf8_t Af = *reinterpret_cast<const bf8_t*>(&W2T[(16*mt+m)*128 + ro]);
        aA[mt] = __builtin_amdgcn_mfma_f32_16x16x32_bf16(Af, BfA, aA[mt], 0,0,0);
        aB[mt] = __builtin_amdgcn_mfma_f32_16x16x32_bf16(Af, BfB, aB[mt], 0,0,0);
      }
    }

    // +b2, LN2 -> z2 (pre-affine), store bf16
    s1A=0.f;s2A=0.f;s1B=0.f;s2B=0.f;
#pragma unroll
    for (int mt=0;mt<8;++mt){
      unsigned bA=b2p[2*mt], bB2=b2p[2*mt+1];
      aA[mt][0]+=uplo(bA); aA[mt][1]+=uphi(bA); aA[mt][2]+=uplo(bB2); aA[mt][3]+=uphi(bB2);
      aB[mt][0]+=uplo(bA); aB[mt][1]+=uphi(bA); aB[mt][2]+=uplo(bB2); aB[mt][3]+=uphi(bB2);
#pragma unroll
      for (int r2=0;r2<4;++r2){
        float vA=aA[mt][r2]; s1A+=vA; s2A+=vA*vA;
        float vB=aB[mt][r2]; s1B+=vB; s2B+=vB*vB;
      }
    }
    s1A += __shfl_xor(s1A,16); s1A += __shfl_xor(s1A,32);
    s2A += __shfl_xor(s2A,16); s2A += __shfl_xor(s2A,32);
    s1B += __shfl_xor(s1B,16); s1B += __shfl_xor(s1B,32);
    s2B += __shfl_xor(s2B,16); s2B += __shfl_xor(s2B,32);
    muA = s1A*(1.f/128.f);
    rsA = rsqrtf(fmaxf(s2A*(1.f/128.f)-muA*muA,0.f)+1e-5f);
    muB = s1B*(1.f/128.f);
    rsB = rsqrtf(fmaxf(s2B*(1.f/128.f)-muB*muB,0.f)+1e-5f);

#pragma unroll
    for (int mt=0;mt<8;++mt){
      {
        float z0=(aA[mt][0]-muA)*rsA, z1=(aA[mt][1]-muA)*rsA;
        float z2v=(aA[mt][2]-muA)*rsA, z3=(aA[mt][3]-muA)*rsA;
        uint2 wv; wv.x=pk2(z0,z1); wv.y=pk2(z2v,z3);
        *reinterpret_cast<uint2*>(&z2[(bo+nA)*CD + 16*mt + 4*g]) = wv;
      }
      {
        float z0=(aB[mt][0]-muB)*rsB, z1=(aB[mt][1]-muB)*rsB;
        float z2v=(aB[mt][2]-muB)*rsB, z3=(aB[mt][3]-muB)*rsB;
        uint2 wv; wv.x=pk2(z0,z1); wv.y=pk2(z2v,z3);
        *reinterpret_cast<uint2*>(&z2[(bo+nB)*CD + 16*mt + 4*g]) = wv;
      }
    }
  }
}

// per-channel max/min of z2 (bf16 scan, coalesced u32 rows)
__global__ __launch_bounds__(256)
void k_cmax(const unsigned short* __restrict__ z2, unsigned* __restrict__ kmax,
            unsigned* __restrict__ kmin)
{
  int b = blockIdx.x >> 5, blk = blockIdx.x & 31;
  int wave = threadIdx.x>>6, lane = threadIdx.x&63;
  float mx0=-1e30f, mx1=-1e30f, mn0=1e30f, mn1=1e30f;
  size_t base = (size_t)(b*NPTS + blk*1250)*CD;
  for (int it = 0; it < 313; ++it){
    int p = it*4 + wave;
    if (p < 1250){
      unsigned v = *reinterpret_cast<const unsigned*>(&z2[base + (size_t)p*CD + 2*lane]);
      float f0 = uplo(v), f1 = uphi(v);
      mx0 = fmaxf(mx0,f0); mn0 = fminf(mn0,f0);
      mx1 = fmaxf(mx1,f1); mn1 = fminf(mn1,f1);
    }
  }
  atomicMax(&kmax[b*CD + 2*lane],   fenc(mx0));
  atomicMax(&kmax[b*CD + 2*lane+1], fenc(mx1));
  atomicMin(&kmin[b*CD + 2*lane],   fenc(mn0));
  atomicMin(&kmin[b*CD + 2*lane+1], fenc(mn1));
}

// global[b][c] = g2*(g2>=0?zmax:zmin)+be2 ; gcomb = b3 + be2@W3top + global@W3bot
__global__ __launch_bounds__(256)
void k_global(const unsigned* __restrict__ kmax, const unsigned* __restrict__ kmin,
              const float* __restrict__ g2, const float* __restrict__ be2,
              const float* __restrict__ W3, const float* __restrict__ b3,
              float* __restrict__ globalv, float* __restrict__ gcomb)
{
  __shared__ float gs[128], bs[128], part[256];
  int b = blockIdx.x;
  int t = threadIdx.x;
  if (t < 128){
    float gg = g2[t];
    float zx = fdec(kmax[b*CD+t]), zn = fdec(kmin[b*CD+t]);
    float gl = (gg>=0.f ? gg*zx : gg*zn) + be2[t];
    gs[t] = gl;
    globalv[b*CD+t] = gl;
    bs[t] = be2[t];
  }
  __syncthreads();
  int c = t & 127, half = t >> 7;
  float accv = 0.f;
  if (half==0){
    for (int k=0;k<128;++k) accv = fmaf(bs[k], W3[k*CD+c], accv);
    accv += b3[c];
  } else {
    for (int k=0;k<128;++k) accv = fmaf(gs[k], W3[(128+k)*CD+c], accv);
  }
  part[t] = accv;
  __syncthreads();
  if (half==0) gcomb[b*CD+c] = part[c] + part[128+c];
}

// ---------------------------------------------------------------------------
// Phase B: u = z2@(g2*W3top) + gcomb; h2=relu(LN3(u)); w=2*sigmoid(h2@W4)
// z2 B-fragments loaded DIRECTLY from global (no repack). 2-tile ILP.
// ---------------------------------------------------------------------------
__global__ __launch_bounds__(256, 2)
void k_mlpB(const unsigned short* __restrict__ z2, const float* __restrict__ g2,
            const float* __restrict__ W3, const float* __restrict__ g3,
            const float* __restrict__ be3, const float* __restrict__ W4,
            const float* __restrict__ masks, const float* __restrict__ gcomb,
            unsigned short* __restrict__ mwT, float* __restrict__ denom)
{
  __shared__ unsigned short W3T[CD*CD];      // 32 KiB swizzled, g2 folded in

  const int tid = threadIdx.x;
  for (int q = tid; q < 8192; q += 256){
    int c = q & 127, k = (q >> 7) * 2;
    float f0 = g2[k]*W3[k*CD + c], f1 = g2[k+1]*W3[(k+1)*CD + c];
    *reinterpret_cast<unsigned*>(&W3T[swzA(c, k)]) = pk2(f0, f1);
  }
  __syncthreads();

  const int wave = tid>>6, lane = tid&63;
  const int m = lane&15, g = lane>>4;
  const int W = blockIdx.x*4 + wave;
  const int b = W/625, wrem = W%625;
  const size_t bo = (size_t)b*NPTS;

  unsigned g3p[16], be3p[16], w4p[16];
  float gcv[32];
#pragma unroll
  for (int j=0;j<16;++j){
    int i0=2*j, i1=2*j+1;
    int c0 = 16*(i0>>2) + 4*g + (i0&3);
    int c1 = 16*(i1>>2) + 4*g + (i1&3);
    g3p[j]  = pk2(g3[c0],  g3[c1]);
    be3p[j] = pk2(be3[c0], be3[c1]);
    w4p[j]  = pk2(W4[c0],  W4[c1]);
    gcv[i0] = gcomb[b*CD + c0];
    gcv[i1] = gcomb[b*CD + c1];
  }

  float dacc = 0.f;

  for (int u = 0; u < 2; ++u){
    const int pb = wrem + 625*u;
    const int nA = 32*pb + m, nB = nA + 16;

    f4_t aA[8], aB[8];
#pragma unroll
    for (int mt=0;mt<8;++mt){ aA[mt]=(f4_t){0.f,0.f,0.f,0.f}; aB[mt]=(f4_t){0.f,0.f,0.f,0.f}; }
#pragma unroll
    for (int ks=0;ks<4;++ks){
      bf8_t BfA = *reinterpret_cast<const bf8_t*>(&z2[(bo+nA)*CD + 32*ks + 8*g]);
      bf8_t BfB = *reinterpret_cast<const bf8_t*>(&z2[(bo+nB)*CD + 32*ks + 8*g]);
      const int ro = (((4*ks+g) ^ (m&7))<<3);
#pragma unroll
      for (int mt=0;mt<8;++mt){
        bf8_t Af = *reinterpret_cast<const bf8_t*>(&W3T[(16*mt+m)*128 + ro]);
        aA[mt] = __builtin_amdgcn_mfma_f32_16x16x32_bf16(Af, BfA, aA[mt], 0,0,0);
        aB[mt] = __builtin_amdgcn_mfma_f32_16x16x32_bf16(Af, BfB, aB[mt], 0,0,0);
      }
    }

    float s1A=0.f,s2A=0.f,s1B=0.f,s2B=0.f;
#pragma unroll
    for (int mt=0;mt<8;++mt)
#pragma unroll
      for (int r2=0;r2<4;++r2){
        float vA = aA[mt][r2] + gcv[mt*4+r2]; aA[mt][r2]=vA; s1A+=vA; s2A+=vA*vA;
        float vB = aB[mt][r2] + gcv[mt*4+r2]; aB[mt][r2]=vB; s1B+=vB; s2B+=vB*vB;
      }
    s1A += __shfl_xor(s1A,16); s1A += __shfl_xor(s1A,32);
    s2A += __shfl_xor(s2A,16); s2A += __shfl_xor(s2A,32);
    s1B += __shfl_xor(s1B,16); s1B += __shfl_xor(s1B,32);
    s2B += __shfl_xor(s2B,16); s2B += __shfl_xor(s2B,32);
    float muA = s1A*(1.f/128.f);
    float rsA = rsqrtf(fmaxf(s2A*(1.f/128.f)-muA*muA,0.f)+1e-5f);
    float muB = s1B*(1.f/128.f);
    float rsB = rsqrtf(fmaxf(s2B*(1.f/128.f)-muB*muB,0.f)+1e-5f);

    float UA = 0.f, UB = 0.f;
#pragma unroll
    for (int mt=0;mt<8;++mt){
      unsigned gA=g3p[2*mt], gB2=g3p[2*mt+1];
      unsigned bA=be3p[2*mt], bB2=be3p[2*mt+1];
      unsigned wA4=w4p[2*mt], wB4=w4p[2*mt+1];
      {
        float h0 = fmaxf(0.f, fmaf((aA[mt][0]-muA)*rsA, uplo(gA), uplo(bA)));
        float h1 = fmaxf(0.f, fmaf((aA[mt][1]-muA)*rsA, uphi(gA), uphi(bA)));
        float h2 = fmaxf(0.f, fmaf((aA[mt][2]-muA)*rsA, uplo(gB2), uplo(bB2)));
        float h3 = fmaxf(0.f, fmaf((aA[mt][3]-muA)*rsA, uphi(gB2), uphi(bB2)));
        UA = fmaf(h0, uplo(wA4), UA); UA = fmaf(h1, uphi(wA4), UA);
        UA = fmaf(h2, uplo(wB4), UA); UA = fmaf(h3, uphi(wB4), UA);
      }
      {
        float h0 = fmaxf(0.f, fmaf((aB[mt][0]-muB)*rsB, uplo(gA), uplo(bA)));
        float h1 = fmaxf(0.f, fmaf((aB[mt][1]-muB)*rsB, uphi(gA), uphi(bA)));
        float h2 = fmaxf(0.f, fmaf((aB[mt][2]-muB)*rsB, uplo(gB2), uplo(bB2)));
        float h3 = fmaxf(0.f, fmaf((aB[mt][3]-muB)*rsB, uphi(gB2), uphi(bB2)));
        UB = fmaf(h0, uplo(wA4), UB); UB = fmaf(h1, uphi(wA4), UB);
        UB = fmaf(h2, uplo(wB4), UB); UB = fmaf(h3, uphi(wB4), UB);
      }
    }
    UA += __shfl_xor(UA,16); UA += __shfl_xor(UA,32);
    UB += __shfl_xor(UB,16); UB += __shfl_xor(UB,32);
    float wA = 2.f/(1.f + __expf(-UA));
    float wB = 2.f/(1.f + __expf(-UB));
    float mskA = masks[(size_t)(4*b+g)*NPTS + nA];
    float mskB = masks[(size_t)(4*b+g)*NPTS + nB];
    mwT[(size_t)(b*16+g)*NPTS + nA] = f2bfu(mskA*wA);
    mwT[(size_t)(b*16+g)*NPTS + nB] = f2bfu(mskB*wB);
    dacc += mskA*wA + mskB*wB;
  }

  dacc += __shfl_xor(dacc,1); dacc += __shfl_xor(dacc,2);
  dacc += __shfl_xor(dacc,4); dacc += __shfl_xor(dacc,8);
  if (m==0) atomicAdd(&denom[b*4+g], dacc);
}

// pooled[c][v] = sum_n feat[c][n] * mwT[v][n]   (MFMA, feat streamed once)
__global__ __launch_bounds__(256)
void k_pool(const float* __restrict__ feat, const unsigned short* __restrict__ mwT,
            float* __restrict__ pool_acc)
{
  int b = blockIdx.x / 125, s = blockIdx.x % 125;
  int wave = threadIdx.x>>6, lane = threadIdx.x&63;
  int m = lane&15, g = lane>>4;
  int mt0 = 2*wave, mt1 = 2*wave+1;
  f4_t p0 = {0.f,0.f,0.f,0.f}, p1 = {0.f,0.f,0.f,0.f};
  const size_t fb = (size_t)b*CD*NPTS;
  for (int kk=0;kk<10;++kk){
    int nb = (s*10+kk)*32 + 8*g;
    bf8_t Bf = *reinterpret_cast<const bf8_t*>(&mwT[(size_t)(b*16+m)*NPTS + nb]);
    const float* fA = &feat[fb + (size_t)(16*mt0+m)*NPTS + nb];
    f4_t x0 = *reinterpret_cast<const f4_t*>(fA);
    f4_t x1 = *reinterpret_cast<const f4_t*>(fA+4);
    bf8_t Af0 = mkbf8(pk2(x0[0],x0[1]),pk2(x0[2],x0[3]),pk2(x1[0],x1[1]),pk2(x1[2],x1[3]));
    p0 = __builtin_amdgcn_mfma_f32_16x16x32_bf16(Af0, Bf, p0, 0,0,0);
    const float* fB = &feat[fb + (size_t)(16*mt1+m)*NPTS + nb];
    f4_t y0 = *reinterpret_cast<const f4_t*>(fB);
    f4_t y1 = *reinterpret_cast<const f4_t*>(fB+4);
    bf8_t Af1 = mkbf8(pk2(y0[0],y0[1]),pk2(y0[2],y0[3]),pk2(y1[0],y1[1]),pk2(y1[2],y1[3]));
    p1 = __builtin_amdgcn_mfma_f32_16x16x32_bf16(Af1, Bf, p1, 0,0,0);
  }
  if (m < 4){
#pragma unroll
    for (int r=0;r<4;++r){
      atomicAdd(&pool_acc[(b*4+m)*CD + 16*mt0+4*g+r], p0[r]);
      atomicAdd(&pool_acc[(b*4+m)*CD + 16*mt1+4*g+r], p1[r]);
    }
  }
}

__global__ __launch_bounds__(256)
void k_final(const float* __restrict__ pool_acc, const float* __restrict__ denom,
             const float* __restrict__ globalv, float* __restrict__ out)
{
  int t = blockIdx.x*256 + threadIdx.x;   // 2048
  int bv = t>>7, c = t&127, b = bv>>2;
  out[t] = pool_acc[t]/(denom[bv]+1e-8f) + globalv[b*CD+c];
}

extern "C" void kernel_launch(void* const* d_in, const int* in_sizes, int n_in,
                              void* d_out, int out_size, void* d_ws,
                              size_t ws_size, hipStream_t stream) {
  const float* xyz  = (const float*)d_in[0];
  const float* feat = (const float*)d_in[1];
  const float* masks= (const float*)d_in[2];
  const float* W1 = (const float*)d_in[3];
  const float* b1 = (const float*)d_in[4];
  const float* g1 = (const float*)d_in[5];
  const float* be1= (const float*)d_in[6];
  const float* W2 = (const float*)d_in[7];
  const float* b2 = (const float*)d_in[8];
  const float* g2 = (const float*)d_in[9];
  const float* be2= (const float*)d_in[10];
  const float* W3 = (const float*)d_in[11];
  const float* b3 = (const float*)d_in[12];
  const float* g3 = (const float*)d_in[13];
  const float* be3= (const float*)d_in[14];
  const float* W4 = (const float*)d_in[15];
  float* out = (float*)d_out;

  char* ws = (char*)d_ws;
  unsigned* kmax    = (unsigned*)ws;                   // 2048 B
  unsigned* kmin    = (unsigned*)(ws + 2048);          // 2048 B
  float*    denom   = (float*)(ws + 4096);             // 64 B
  float*    pool_acc= (float*)(ws + 4352);             // 8192 B
  float*    globalv = (float*)(ws + 12544);            // 2048 B
  float*    gcomb   = (float*)(ws + 14592);            // 2048 B
  unsigned short* mwT = (unsigned short*)(ws + 16640); // 5.12 MB
  unsigned short* z2  = (unsigned short*)(ws + 5136640); // 40.96 MB

  k_init<<<16, 256, 0, stream>>>(kmax, kmin, denom, pool_acc);
  k_mlpA<<<625, 256, 0, stream>>>(xyz, W1, b1, g1, be1, W2, b2, z2);
  k_cmax<<<128, 256, 0, stream>>>(z2, kmax, kmin);
  k_global<<<4, 256, 0, stream>>>(kmax, kmin, g2, be2, W3, b3, globalv, gcomb);
  k_mlpB<<<625, 256, 0, stream>>>(z2, g2, W3, g3, be3, W4, masks, gcomb, mwT, denom);
  k_pool<<<500, 256, 0, stream>>>(feat, mwT, pool_acc);
  k_final<<<8, 256, 0, stream>>>(pool_acc, denom, globalv, out);
}

// Round 4
// 242.880 us; speedup vs baseline: 1.1891x; 1.1891x over previous
//
#include <hip/hip_runtime.h>
#include <stdint.h>

// GeoAwarePooling B=4, N=40000, C=128, V=4.
// xyz is broadcast across views -> per-point MLP runs once over B*N points.
// v4: K=16 MFMA chain (GEMM output C/D layout == next GEMM's B layout, so no
// transpose at all), W2/W3 pre-packed as per-lane K=16 A-frags in 32KB LDS,
// z2 round-trip in lane-chunk layout (fully coalesced dwordx4), per-channel
// max/min fused into phase A as packed-bf16 register tracking.

#define NPTS 40000
#define CD   128

typedef __attribute__((ext_vector_type(4))) short bf4_t;
typedef __attribute__((ext_vector_type(8))) short bf8_t;
typedef __attribute__((ext_vector_type(4))) float f4_t;

union u2bf4 { uint2 u; bf4_t s; };

__device__ __forceinline__ unsigned short f2bfu(float f){
  unsigned u = __float_as_uint(f);
  u += 0x7FFFu + ((u>>16)&1u);               // RNE
  return (unsigned short)(u>>16);
}
__device__ __forceinline__ float bfhi_f(float f){   // f rounded to bf16, as f32
  return __uint_as_float(((unsigned)f2bfu(f))<<16);
}
__device__ __forceinline__ unsigned pk2(float a, float b){
  return (unsigned)f2bfu(a) | ((unsigned)f2bfu(b)<<16);
}
__device__ __forceinline__ unsigned pkt(float a, float b){  // truncating pack
  return (__float_as_uint(a)>>16) | (__float_as_uint(b) & 0xFFFF0000u);
}
__device__ __forceinline__ float uplo(unsigned u){ return __uint_as_float(u<<16); }
__device__ __forceinline__ float uphi(unsigned u){ return __uint_as_float(u & 0xFFFF0000u); }
__device__ __forceinline__ unsigned fenc(float f){  // order-preserving key
  unsigned u = __float_as_uint(f);
  return (u & 0x80000000u) ? ~u : (u | 0x80000000u);
}
__device__ __forceinline__ float fdec(unsigned k){
  return (k & 0x80000000u) ? __uint_as_float(k & 0x7FFFFFFFu) : __uint_as_float(~k);
}
__device__ __forceinline__ bf8_t mkbf8(unsigned a,unsigned b,unsigned c,unsigned d){
  union{ bf8_t v; unsigned u[4]; } r;
  r.u[0]=a; r.u[1]=b; r.u[2]=c; r.u[3]=d;
  return r.v;
}

#if __has_builtin(__builtin_amdgcn_mfma_f32_16x16x16bf16_1k)
__device__ __forceinline__ f4_t mfma16(bf4_t a, bf4_t b, f4_t c){
  return __builtin_amdgcn_mfma_f32_16x16x16bf16_1k(a, b, c, 0, 0, 0);
}
#else
// emulate K=16 with zero-padded K=32: logical slot 4g+r -> physical 8g+r on
// BOTH operands, so the dot product is identical.
__device__ __forceinline__ f4_t mfma16(bf4_t a, bf4_t b, f4_t c){
  union{ bf8_t v; bf4_t h[2]; } A, B;
  bf4_t z = {0,0,0,0};
  A.h[0]=a; A.h[1]=z; B.h[0]=b; B.h[1]=z;
  return __builtin_amdgcn_mfma_f32_16x16x32_bf16(A.v, B.v, c, 0, 0, 0);
}
#endif

__global__ __launch_bounds__(256)
void k_init(unsigned* __restrict__ kmax, unsigned* __restrict__ kmin,
            float* __restrict__ denom, float* __restrict__ pool_acc){
  int t = blockIdx.x*256 + threadIdx.x;
  if (t < 512){ kmax[t] = 0u; kmin[t] = 0xFFFFFFFFu; }
  if (t < 16) denom[t] = 0.f;
  if (t < 2048) pool_acc[t] = 0.f;
}

// ---------------------------------------------------------------------------
// Phase A: y=xyz@W1+b1 (K=16 MFMA, hi/lo split, fp32-exact); h=relu(LN1(y));
// z2=(h@W2+b2 normalized, pre-affine). D-layout feeds GEMM2's B directly.
// Stores z2 in lane-chunk layout; tracks per-channel max/min in packed bf16.
// Wave handles 4 consecutive 16-pt tiles, all in one batch.
// ---------------------------------------------------------------------------
__global__ __launch_bounds__(256)
void k_A(const float* __restrict__ xyz,
         const float* __restrict__ W1, const float* __restrict__ b1,
         const float* __restrict__ g1, const float* __restrict__ be1,
         const float* __restrict__ W2, const float* __restrict__ b2,
         unsigned* __restrict__ z2u,
         unsigned* __restrict__ kmax, unsigned* __restrict__ kmin)
{
  __shared__ uint2 W2F[4096];   // 32 KiB: per-lane K=16 A-frags of W2^T

  const int tid = threadIdx.x;
  for (int idx = tid; idx < 4096; idx += 256){
    int fid = idx >> 6, l = idx & 63;
    int mti = fid >> 3, mto = fid & 7;
    int lm = l & 15, lg = l >> 4;
    int ci0 = 16*mti + 4*lg, co = 16*mto + lm;
    uint2 v;
    v.x = pk2(W2[(ci0+0)*CD+co], W2[(ci0+1)*CD+co]);
    v.y = pk2(W2[(ci0+2)*CD+co], W2[(ci0+3)*CD+co]);
    W2F[idx] = v;
  }
  __syncthreads();

  const int wave = tid>>6, lane = tid&63;
  const int m = lane&15, g = lane>>4;
  const int wid = blockIdx.x*4 + wave;    // 0..2499
  const int b = wid/625;                  // one batch per wave
  const float* xyzb = xyz + (size_t)(3*b)*NPTS;

  // GEMM1 A-frags: channel c=16mt+m, slots 4g..4g+3 of the 11-slot hi/lo plan
  uint2 A1[8];
#pragma unroll
  for (int mt=0; mt<8; ++mt){
    int c = 16*mt + m;
    float w0=W1[c], w1=W1[CD+c], w2=W1[2*CD+c], bb=b1[c];
    uint2 v; v.x=0u; v.y=0u;
    if (g==0){ v.x = pk2(w0,w1); v.y = pk2(w2,w0); }
    else if (g==1){ v.x = pk2(w1,w2); v.y = pk2(w0-bfhi_f(w0), w1-bfhi_f(w1)); }
    else if (g==2){ v.x = pk2(w2-bfhi_f(w2), bb); v.y = pk2(bb-bfhi_f(bb), 0.f); }
    A1[mt] = v;
  }

  // per-lane affine params (channels c=16mt+4g+r), bf16-packed
  unsigned g1p[16], be1p[16], b2p[16];
#pragma unroll
  for (int j=0;j<16;++j){
    int i0=2*j, i1=2*j+1;
    int c0 = 16*(i0>>2) + 4*g + (i0&3);
    int c1 = 16*(i1>>2) + 4*g + (i1&3);
    g1p[j]  = pk2(g1[c0],  g1[c1]);
    be1p[j] = pk2(be1[c0], be1[c1]);
    b2p[j]  = pk2(b2[c0],  b2[c1]);
  }

  unsigned zmx[16], zmn[16];
  const unsigned NEG = pkt(-1e30f,-1e30f), POS = pkt(1e30f,1e30f);
#pragma unroll
  for (int j=0;j<16;++j){ zmx[j]=NEG; zmn[j]=POS; }

  for (int u = 0; u < 4; ++u){
    const int it = wid*4 + u;             // global tile id 0..9999
    const int n = (it - b*2500)*16 + m;   // within-batch point
    float px = xyzb[n], py = xyzb[NPTS+n], pz = xyzb[2*NPTS+n];

    u2bf4 B1; B1.u.x = 0u; B1.u.y = 0u;
    if (g==0){ B1.u.x = pk2(px,py); B1.u.y = pk2(pz, px-bfhi_f(px)); }
    else if (g==1){ B1.u.x = pk2(py-bfhi_f(py), pz-bfhi_f(pz)); B1.u.y = pk2(px,py); }
    else if (g==2){ B1.u.x = pk2(pz, 1.0f); B1.u.y = pk2(1.0f, 0.f); }

    f4_t acc[8];
#pragma unroll
    for (int mt=0;mt<8;++mt){
      u2bf4 Af; Af.u = A1[mt];
      acc[mt] = mfma16(Af.s, B1.s, (f4_t){0.f,0.f,0.f,0.f});
    }

    // LN1
    float s1=0.f, s2=0.f;
#pragma unroll
    for (int mt=0;mt<8;++mt)
#pragma unroll
      for (int r=0;r<4;++r){ float v=acc[mt][r]; s1+=v; s2=fmaf(v,v,s2); }
    s1 += __shfl_xor(s1,16); s1 += __shfl_xor(s1,32);
    s2 += __shfl_xor(s2,16); s2 += __shfl_xor(s2,32);
    float mu = s1*(1.f/128.f);
    float rs = rsqrtf(fmaxf(s2*(1.f/128.f)-mu*mu,0.f)+1e-5f);

    // affine+relu -> packed h (this IS GEMM2's B-fragment, no movement)
    unsigned hu[16];
#pragma unroll
    for (int mt=0;mt<8;++mt){
      unsigned gA=g1p[2*mt], gB=g1p[2*mt+1], bA=be1p[2*mt], bB=be1p[2*mt+1];
      float h0 = fmaxf(0.f, fmaf((acc[mt][0]-mu)*rs, uplo(gA), uplo(bA)));
      float h1 = fmaxf(0.f, fmaf((acc[mt][1]-mu)*rs, uphi(gA), uphi(bA)));
      float h2 = fmaxf(0.f, fmaf((acc[mt][2]-mu)*rs, uplo(gB), uplo(bB)));
      float h3 = fmaxf(0.f, fmaf((acc[mt][3]-mu)*rs, uphi(gB), uphi(bB)));
      hu[2*mt]   = pk2(h0,h1);
      hu[2*mt+1] = pk2(h2,h3);
    }

    // GEMM2: 64 K=16 MFMAs, A from LDS (conflict-free b64 at lane*8)
    f4_t a2[8];
#pragma unroll
    for (int mt=0;mt<8;++mt) a2[mt]=(f4_t){0.f,0.f,0.f,0.f};
#pragma unroll
    for (int mti=0;mti<8;++mti){
      u2bf4 Bf; Bf.u.x = hu[2*mti]; Bf.u.y = hu[2*mti+1];
#pragma unroll
      for (int mto=0;mto<8;++mto){
        u2bf4 Af; Af.u = W2F[(mti*8+mto)*64 + lane];
        a2[mto] = mfma16(Af.s, Bf.s, a2[mto]);
      }
    }

    // +b2, LN2 -> z (pre-affine)
    s1=0.f; s2=0.f;
#pragma unroll
    for (int mt=0;mt<8;++mt){
      unsigned bA=b2p[2*mt], bB=b2p[2*mt+1];
      a2[mt][0]+=uplo(bA); a2[mt][1]+=uphi(bA);
      a2[mt][2]+=uplo(bB); a2[mt][3]+=uphi(bB);
#pragma unroll
      for (int r=0;r<4;++r){ float v=a2[mt][r]; s1+=v; s2=fmaf(v,v,s2); }
    }
    s1 += __shfl_xor(s1,16); s1 += __shfl_xor(s1,32);
    s2 += __shfl_xor(s2,16); s2 += __shfl_xor(s2,32);
    mu = s1*(1.f/128.f);
    rs = rsqrtf(fmaxf(s2*(1.f/128.f)-mu*mu,0.f)+1e-5f);

    unsigned zu[16];
#pragma unroll
    for (int mt=0;mt<8;++mt){
      float z0=(a2[mt][0]-mu)*rs, z1=(a2[mt][1]-mu)*rs;
      float z2v=(a2[mt][2]-mu)*rs, z3=(a2[mt][3]-mu)*rs;
      zu[2*mt]   = pk2(z0,z1);
      zu[2*mt+1] = pk2(z2v,z3);
      zmx[2*mt]   = pkt(fmaxf(uplo(zmx[2*mt]),  z0), fmaxf(uphi(zmx[2*mt]),  z1));
      zmx[2*mt+1] = pkt(fmaxf(uplo(zmx[2*mt+1]),z2v), fmaxf(uphi(zmx[2*mt+1]),z3));
      zmn[2*mt]   = pkt(fminf(uplo(zmn[2*mt]),  z0), fminf(uphi(zmn[2*mt]),  z1));
      zmn[2*mt+1] = pkt(fminf(uplo(zmn[2*mt+1]),z2v), fminf(uphi(zmn[2*mt+1]),z3));
    }

    // coalesced store: 4 x dwordx4, 1 KB contiguous per inst
    size_t base = (size_t)it*1024 + lane*4;
#pragma unroll
    for (int s=0;s<4;++s){
      uint4 v; v.x=zu[4*s]; v.y=zu[4*s+1]; v.z=zu[4*s+2]; v.w=zu[4*s+3];
      *reinterpret_cast<uint4*>(&z2u[base + s*256]) = v;
    }
  }

  // reduce extremes across m, one atomic set per (g,channel)
#pragma unroll
  for (int j=0;j<16;++j){
    float xlo = uplo(zmx[j]), xhi = uphi(zmx[j]);
    float nlo = uplo(zmn[j]), nhi = uphi(zmn[j]);
#pragma unroll
    for (int o=1;o<16;o<<=1){
      xlo = fmaxf(xlo, __shfl_xor(xlo,o)); xhi = fmaxf(xhi, __shfl_xor(xhi,o));
      nlo = fminf(nlo, __shfl_xor(nlo,o)); nhi = fminf(nhi, __shfl_xor(nhi,o));
    }
    if (m==0){
      int mt=j>>1, h=j&1; int c = 16*mt + 4*g + 2*h;
      atomicMax(&kmax[b*CD+c],   fenc(xlo));
      atomicMax(&kmax[b*CD+c+1], fenc(xhi));
      atomicMin(&kmin[b*CD+c],   fenc(nlo));
      atomicMin(&kmin[b*CD+c+1], fenc(nhi));
    }
  }
}

// global[b][c] = g2*(g2>=0?zmax:zmin)+be2 ; gcomb = b3 + be2@W3top + global@W3bot
__global__ __launch_bounds__(256)
void k_global(const unsigned* __restrict__ kmax, const unsigned* __restrict__ kmin,
              const float* __restrict__ g2, const float* __restrict__ be2,
              const float* __restrict__ W3, const float* __restrict__ b3,
              float* __restrict__ globalv, float* __restrict__ gcomb)
{
  __shared__ float gs[128], bs[128], part[256];
  int b = blockIdx.x;
  int t = threadIdx.x;
  if (t < 128){
    float gg = g2[t];
    float zx = fdec(kmax[b*CD+t]), zn = fdec(kmin[b*CD+t]);
    float gl = (gg>=0.f ? gg*zx : gg*zn) + be2[t];
    gs[t] = gl;
    globalv[b*CD+t] = gl;
    bs[t] = be2[t];
  }
  __syncthreads();
  int c = t & 127, half = t >> 7;
  float accv = 0.f;
  if (half==0){
    for (int k=0;k<128;++k) accv = fmaf(bs[k], W3[k*CD+c], accv);
    accv += b3[c];
  } else {
    for (int k=0;k<128;++k) accv = fmaf(gs[k], W3[(128+k)*CD+c], accv);
  }
  part[t] = accv;
  __syncthreads();
  if (half==0) gcomb[b*CD+c] = part[c] + part[128+c];
}

// ---------------------------------------------------------------------------
// Phase B: u = z2@(g2*W3top) + gcomb; h2=relu(LN3(u)); w=2*sigmoid(h2@W4)
// z2 reloaded coalesced into the exact register state; same K=16 chain.
// ---------------------------------------------------------------------------
__global__ __launch_bounds__(256)
void k_B(const unsigned* __restrict__ z2u, const float* __restrict__ g2,
         const float* __restrict__ W3, const float* __restrict__ g3,
         const float* __restrict__ be3, const float* __restrict__ W4,
         const float* __restrict__ masks, const float* __restrict__ gcomb,
         unsigned short* __restrict__ mwT, float* __restrict__ denom)
{
  __shared__ uint2 W3F[4096];   // g2 folded into W3top rows

  const int tid = threadIdx.x;
  for (int idx = tid; idx < 4096; idx += 256){
    int fid = idx >> 6, l = idx & 63;
    int mti = fid >> 3, mto = fid & 7;
    int lm = l & 15, lg = l >> 4;
    int ci0 = 16*mti + 4*lg, co = 16*mto + lm;
    uint2 v;
    v.x = pk2(g2[ci0+0]*W3[(ci0+0)*CD+co], g2[ci0+1]*W3[(ci0+1)*CD+co]);
    v.y = pk2(g2[ci0+2]*W3[(ci0+2)*CD+co], g2[ci0+3]*W3[(ci0+3)*CD+co]);
    W3F[idx] = v;
  }
  __syncthreads();

  const int wave = tid>>6, lane = tid&63;
  const int m = lane&15, g = lane>>4;
  const int wid = blockIdx.x*4 + wave;
  const int b = wid/625;

  unsigned g3p[16], be3p[16], w4p[16];
  float gcv[32];
#pragma unroll
  for (int j=0;j<16;++j){
    int i0=2*j, i1=2*j+1;
    int c0 = 16*(i0>>2) + 4*g + (i0&3);
    int c1 = 16*(i1>>2) + 4*g + (i1&3);
    g3p[j]  = pk2(g3[c0],  g3[c1]);
    be3p[j] = pk2(be3[c0], be3[c1]);
    w4p[j]  = pk2(W4[c0],  W4[c1]);
    gcv[i0] = gcomb[b*CD + c0];
    gcv[i1] = gcomb[b*CD + c1];
  }

  float dacc = 0.f;

  for (int u = 0; u < 4; ++u){
    const int it = wid*4 + u;
    const int n = (it - b*2500)*16 + m;

    unsigned zu[16];
    size_t base = (size_t)it*1024 + lane*4;
#pragma unroll
    for (int s=0;s<4;++s){
      uint4 v = *reinterpret_cast<const uint4*>(&z2u[base + s*256]);
      zu[4*s]=v.x; zu[4*s+1]=v.y; zu[4*s+2]=v.z; zu[4*s+3]=v.w;
    }

    f4_t a3[8];
#pragma unroll
    for (int mt=0;mt<8;++mt) a3[mt]=(f4_t){0.f,0.f,0.f,0.f};
#pragma unroll
    for (int mti=0;mti<8;++mti){
      u2bf4 Bf; Bf.u.x = zu[2*mti]; Bf.u.y = zu[2*mti+1];
#pragma unroll
      for (int mto=0;mto<8;++mto){
        u2bf4 Af; Af.u = W3F[(mti*8+mto)*64 + lane];
        a3[mto] = mfma16(Af.s, Bf.s, a3[mto]);
      }
    }

    float s1=0.f, s2=0.f;
#pragma unroll
    for (int mt=0;mt<8;++mt)
#pragma unroll
      for (int r=0;r<4;++r){
        float v = a3[mt][r] + gcv[4*mt+r]; a3[mt][r]=v; s1+=v; s2=fmaf(v,v,s2);
      }
    s1 += __shfl_xor(s1,16); s1 += __shfl_xor(s1,32);
    s2 += __shfl_xor(s2,16); s2 += __shfl_xor(s2,32);
    float mu = s1*(1.f/128.f);
    float rs = rsqrtf(fmaxf(s2*(1.f/128.f)-mu*mu,0.f)+1e-5f);

    float U = 0.f;
#pragma unroll
    for (int mt=0;mt<8;++mt){
      unsigned gA=g3p[2*mt], gB=g3p[2*mt+1];
      unsigned bA=be3p[2*mt], bB=be3p[2*mt+1];
      unsigned wA=w4p[2*mt], wB=w4p[2*mt+1];
      float h0 = fmaxf(0.f, fmaf((a3[mt][0]-mu)*rs, uplo(gA), uplo(bA)));
      float h1 = fmaxf(0.f, fmaf((a3[mt][1]-mu)*rs, uphi(gA), uphi(bA)));
      float h2 = fmaxf(0.f, fmaf((a3[mt][2]-mu)*rs, uplo(gB), uplo(bB)));
      float h3 = fmaxf(0.f, fmaf((a3[mt][3]-mu)*rs, uphi(gB), uphi(bB)));
      U = fmaf(h0, uplo(wA), U); U = fmaf(h1, uphi(wA), U);
      U = fmaf(h2, uplo(wB), U); U = fmaf(h3, uphi(wB), U);
    }
    U += __shfl_xor(U,16); U += __shfl_xor(U,32);
    float w = 2.f/(1.f + __expf(-U));
    float msk = masks[(size_t)(4*b+g)*NPTS + n];
    mwT[(size_t)(b*16+g)*NPTS + n] = f2bfu(msk*w);
    dacc += msk*w;
  }

  dacc += __shfl_xor(dacc,1); dacc += __shfl_xor(dacc,2);
  dacc += __shfl_xor(dacc,4); dacc += __shfl_xor(dacc,8);
  if (m==0) atomicAdd(&denom[b*4+g], dacc);
}

// pooled[c][v] = sum_n feat[c][n] * mwT[v][n]   (MFMA, feat streamed once)
__global__ __launch_bounds__(256)
void k_pool(const float* __restrict__ feat, const unsigned short* __restrict__ mwT,
            float* __restrict__ pool_acc)
{
  int b = blockIdx.x / 125, s = blockIdx.x % 125;
  int wave = threadIdx.x>>6, lane = threadIdx.x&63;
  int m = lane&15, g = lane>>4;
  int mt0 = 2*wave, mt1 = 2*wave+1;
  f4_t p0 = {0.f,0.f,0.f,0.f}, p1 = {0.f,0.f,0.f,0.f};
  const size_t fb = (size_t)b*CD*NPTS;
  for (int kk=0;kk<10;++kk){
    int nb = (s*10+kk)*32 + 8*g;
    bf8_t Bf = *reinterpret_cast<const bf8_t*>(&mwT[(size_t)(b*16+m)*NPTS + nb]);
    const float* fA = &feat[fb + (size_t)(16*mt0+m)*NPTS + nb];
    f4_t x0 = *reinterpret_cast<const f4_t*>(fA);
    f4_t x1 = *reinterpret_cast<const f4_t*>(fA+4);
    bf8_t Af0 = mkbf8(pk2(x0[0],x0[1]),pk2(x0[2],x0[3]),pk2(x1[0],x1[1]),pk2(x1[2],x1[3]));
    p0 = __builtin_amdgcn_mfma_f32_16x16x32_bf16(Af0, Bf, p0, 0,0,0);
    const float* fB = &feat[fb + (size_t)(16*mt1+m)*NPTS + nb];
    f4_t y0 = *reinterpret_cast<const f4_t*>(fB);
    f4_t y1 = *reinterpret_cast<const f4_t*>(fB+4);
    bf8_t Af1 = mkbf8(pk2(y0[0],y0[1]),pk2(y0[2],y0[3]),pk2(y1[0],y1[1]),pk2(y1[2],y1[3]));
    p1 = __builtin_amdgcn_mfma_f32_16x16x32_bf16(Af1, Bf, p1, 0,0,0);
  }
  if (m < 4){
#pragma unroll
    for (int r=0;r<4;++r){
      atomicAdd(&pool_acc[(b*4+m)*CD + 16*mt0+4*g+r], p0[r]);
      atomicAdd(&pool_acc[(b*4+m)*CD + 16*mt1+4*g+r], p1[r]);
    }
  }
}

__global__ __launch_bounds__(256)
void k_final(const float* __restrict__ pool_acc, const float* __restrict__ denom,
             const float* __restrict__ globalv, float* __restrict__ out)
{
  int t = blockIdx.x*256 + threadIdx.x;   // 2048
  int bv = t>>7, c = t&127, b = bv>>2;
  out[t] = pool_acc[t]/(denom[bv]+1e-8f) + globalv[b*CD+c];
}

extern "C" void kernel_launch(void* const* d_in, const int* in_sizes, int n_in,
                              void* d_out, int out_size, void* d_ws,
                              size_t ws_size, hipStream_t stream) {
  const float* xyz  = (const float*)d_in[0];
  const float* feat = (const float*)d_in[1];
  const float* masks= (const float*)d_in[2];
  const float* W1 = (const float*)d_in[3];
  const float* b1 = (const float*)d_in[4];
  const float* g1 = (const float*)d_in[5];
  const float* be1= (const float*)d_in[6];
  const float* W2 = (const float*)d_in[7];
  const float* b2 = (const float*)d_in[8];
  const float* g2 = (const float*)d_in[9];
  const float* be2= (const float*)d_in[10];
  const float* W3 = (const float*)d_in[11];
  const float* b3 = (const float*)d_in[12];
  const float* g3 = (const float*)d_in[13];
  const float* be3= (const float*)d_in[14];
  const float* W4 = (const float*)d_in[15];
  float* out = (float*)d_out;

  char* ws = (char*)d_ws;
  unsigned* kmax    = (unsigned*)ws;                   // 2048 B
  unsigned* kmin    = (unsigned*)(ws + 2048);          // 2048 B
  float*    denom   = (float*)(ws + 4096);             // 64 B
  float*    pool_acc= (float*)(ws + 4352);             // 8192 B
  float*    globalv = (float*)(ws + 12544);            // 2048 B
  float*    gcomb   = (float*)(ws + 14592);            // 2048 B
  unsigned short* mwT = (unsigned short*)(ws + 16640); // 5.12 MB
  unsigned* z2u     = (unsigned*)(ws + 5136640);       // 40.96 MB

  k_init<<<16, 256, 0, stream>>>(kmax, kmin, denom, pool_acc);
  k_A<<<625, 256, 0, stream>>>(xyz, W1, b1, g1, be1, W2, b2, z2u, kmax, kmin);
  k_global<<<4, 256, 0, stream>>>(kmax, kmin, g2, be2, W3, b3, globalv, gcomb);
  k_B<<<625, 256, 0, stream>>>(z2u, g2, W3, g3, be3, W4, masks, gcomb, mwT, denom);
  k_pool<<<500, 256, 0, stream>>>(feat, mwT, pool_acc);
  k_final<<<8, 256, 0, stream>>>(pool_acc, denom, globalv, out);
}